// Round 1
// baseline (2022.947 us; speedup 1.0000x reference)
//
#include <hip/hip_runtime.h>
#include <math.h>

#define NN 50000
#define NE 640000
#define DD 128

// ws layout (float offsets)
#define OFF_UVBC 0L
#define OFF_AGG   25600000L          // N*512 floats of UVBC before this
#define OFF_WPACK 32000000L          // + N*128 agg
#define OFF_BPACK 32065536L          // + 512*128 packed W
#define OFF_STATS 32066048L          // + 512 packed bias; stats: esum,esq,nsum,nsq,escale,eshift,nscale,nshift (8*128)

// ---------------- prep: zero agg + stats, pack weights/biases ----------------
__global__ void k_prep(const float* __restrict__ Wu, const float* __restrict__ Wv,
                       const float* __restrict__ WB, const float* __restrict__ WC,
                       const float* __restrict__ bu, const float* __restrict__ bv,
                       const float* __restrict__ bB, const float* __restrict__ bC,
                       float* __restrict__ ws) {
  long i = (long)blockIdx.x * 256 + threadIdx.x;
  const long NAGG4 = (long)NN * DD / 4;  // 1,600,000 float4 slots
  if (i < NAGG4) {
    ((float4*)(ws + OFF_AGG))[i] = make_float4(0.f, 0.f, 0.f, 0.f);
    return;
  }
  long j = i - NAGG4;
  if (j < 65536) {
    int w = (int)(j >> 14), idx = (int)(j & 16383);
    const float* src = (w == 0) ? Wu : (w == 1) ? Wv : (w == 2) ? WB : WC;
    ws[OFF_WPACK + (long)w * 16384 + idx] = src[idx];
    return;
  }
  j -= 65536;
  if (j < 512) {
    int w = (int)(j >> 7), idx = (int)(j & 127);
    const float* src = (w == 0) ? bu : (w == 1) ? bv : (w == 2) ? bB : bC;
    ws[OFF_BPACK + j] = src[idx];
    return;
  }
  j -= 512;
  if (j < 512) ws[OFF_STATS + j] = 0.f;  // esum esq nsum nsq
}

// ---------------- node GEMM: UVBC[N][512] = x @ [Wu|Wv|WB|WC].T + b ----------------
__global__ __launch_bounds__(256) void k_node_gemm(const float* __restrict__ x,
                                                   const float* __restrict__ Wp,
                                                   const float* __restrict__ bp,
                                                   float* __restrict__ out) {
  __shared__ float xt[32][132];  // transposed x tile: xt[k][row]
  __shared__ float wt[32][132];  // transposed w tile: wt[k][feat]
  const int t = threadIdx.x;
  const int tx = t & 15, ty = t >> 4;
  const int rb = blockIdx.x * 128;
  const int fb = blockIdx.y * 128;
  float acc[8][8];
#pragma unroll
  for (int i = 0; i < 8; i++)
#pragma unroll
    for (int j = 0; j < 8; j++) acc[i][j] = 0.f;

  for (int kc = 0; kc < DD; kc += 32) {
#pragma unroll
    for (int s = 0; s < 4; s++) {
      int slot = t + s * 256;            // 0..1023
      int r = slot >> 3;                 // 0..127
      int kq = (slot & 7) << 2;          // 0,4,..,28
      int gr = rb + r;
      float4 v = make_float4(0.f, 0.f, 0.f, 0.f);
      if (gr < NN) v = *(const float4*)(x + (long)gr * DD + kc + kq);
      xt[kq][r] = v.x; xt[kq + 1][r] = v.y; xt[kq + 2][r] = v.z; xt[kq + 3][r] = v.w;
      float4 w = *(const float4*)(Wp + (long)(fb + r) * DD + kc + kq);
      wt[kq][r] = w.x; wt[kq + 1][r] = w.y; wt[kq + 2][r] = w.z; wt[kq + 3][r] = w.w;
    }
    __syncthreads();
#pragma unroll
    for (int k = 0; k < 32; k++) {
      float4 a0 = *(const float4*)&xt[k][ty * 8];
      float4 a1 = *(const float4*)&xt[k][ty * 8 + 4];
      float4 b0 = *(const float4*)&wt[k][tx * 8];
      float4 b1 = *(const float4*)&wt[k][tx * 8 + 4];
      float a[8] = {a0.x, a0.y, a0.z, a0.w, a1.x, a1.y, a1.z, a1.w};
      float b[8] = {b0.x, b0.y, b0.z, b0.w, b1.x, b1.y, b1.z, b1.w};
#pragma unroll
      for (int i = 0; i < 8; i++)
#pragma unroll
        for (int j = 0; j < 8; j++) acc[i][j] = fmaf(a[i], b[j], acc[i][j]);
    }
    __syncthreads();
  }
  float bb[8];
  *(float4*)&bb[0] = *(const float4*)(bp + fb + tx * 8);
  *(float4*)&bb[4] = *(const float4*)(bp + fb + tx * 8 + 4);
#pragma unroll
  for (int i = 0; i < 8; i++) {
    int gr = rb + ty * 8 + i;
    if (gr < NN) {
      float* op = out + (long)gr * 512 + fb + tx * 8;
      *(float4*)op = make_float4(acc[i][0] + bb[0], acc[i][1] + bb[1], acc[i][2] + bb[2], acc[i][3] + bb[3]);
      *(float4*)(op + 4) = make_float4(acc[i][4] + bb[4], acc[i][5] + bb[5], acc[i][6] + bb[6], acc[i][7] + bb[7]);
    }
  }
}

// ---- edge GEMM: edge_in = ea@WA.T + bA + Bx[row] + Cx[col]; fused BN stats ----
__global__ __launch_bounds__(256) void k_edge_gemm(const float* __restrict__ ea,
                                                   const float* __restrict__ WA,
                                                   const float* __restrict__ bA,
                                                   const int* __restrict__ rowi,
                                                   const int* __restrict__ coli,
                                                   const float* __restrict__ UVBC,
                                                   float* __restrict__ edge_in,
                                                   float* __restrict__ esum,
                                                   float* __restrict__ esq) {
  __shared__ float xt[32][132];
  __shared__ float wt[32][132];
  const int t = threadIdx.x;
  const int tx = t & 15, ty = t >> 4;
  const int rb = blockIdx.x * 128;  // E divisible by 128
  float acc[8][8];
#pragma unroll
  for (int i = 0; i < 8; i++)
#pragma unroll
    for (int j = 0; j < 8; j++) acc[i][j] = 0.f;

  for (int kc = 0; kc < DD; kc += 32) {
#pragma unroll
    for (int s = 0; s < 4; s++) {
      int slot = t + s * 256;
      int r = slot >> 3;
      int kq = (slot & 7) << 2;
      float4 v = *(const float4*)(ea + (long)(rb + r) * DD + kc + kq);
      xt[kq][r] = v.x; xt[kq + 1][r] = v.y; xt[kq + 2][r] = v.z; xt[kq + 3][r] = v.w;
      float4 w = *(const float4*)(WA + (long)r * DD + kc + kq);
      wt[kq][r] = w.x; wt[kq + 1][r] = w.y; wt[kq + 2][r] = w.z; wt[kq + 3][r] = w.w;
    }
    __syncthreads();
#pragma unroll
    for (int k = 0; k < 32; k++) {
      float4 a0 = *(const float4*)&xt[k][ty * 8];
      float4 a1 = *(const float4*)&xt[k][ty * 8 + 4];
      float4 b0 = *(const float4*)&wt[k][tx * 8];
      float4 b1 = *(const float4*)&wt[k][tx * 8 + 4];
      float a[8] = {a0.x, a0.y, a0.z, a0.w, a1.x, a1.y, a1.z, a1.w};
      float b[8] = {b0.x, b0.y, b0.z, b0.w, b1.x, b1.y, b1.z, b1.w};
#pragma unroll
      for (int i = 0; i < 8; i++)
#pragma unroll
        for (int j = 0; j < 8; j++) acc[i][j] = fmaf(a[i], b[j], acc[i][j]);
    }
    __syncthreads();
  }
  float bb[8];
  *(float4*)&bb[0] = *(const float4*)(bA + tx * 8);
  *(float4*)&bb[4] = *(const float4*)(bA + tx * 8 + 4);
  float s[8], q[8];
#pragma unroll
  for (int j = 0; j < 8; j++) { s[j] = 0.f; q[j] = 0.f; }
#pragma unroll
  for (int i = 0; i < 8; i++) {
    int e = rb + ty * 8 + i;
    int ri = rowi[e], ci = coli[e];
    const float* gB = UVBC + (long)ri * 512 + 256 + tx * 8;
    const float* gC = UVBC + (long)ci * 512 + 384 + tx * 8;
    float4 g0 = *(const float4*)gB, g1 = *(const float4*)(gB + 4);
    float4 h0 = *(const float4*)gC, h1 = *(const float4*)(gC + 4);
    float v[8];
    v[0] = acc[i][0] + bb[0] + g0.x + h0.x;
    v[1] = acc[i][1] + bb[1] + g0.y + h0.y;
    v[2] = acc[i][2] + bb[2] + g0.z + h0.z;
    v[3] = acc[i][3] + bb[3] + g0.w + h0.w;
    v[4] = acc[i][4] + bb[4] + g1.x + h1.x;
    v[5] = acc[i][5] + bb[5] + g1.y + h1.y;
    v[6] = acc[i][6] + bb[6] + g1.z + h1.z;
    v[7] = acc[i][7] + bb[7] + g1.w + h1.w;
    float* op = edge_in + (long)e * DD + tx * 8;
    *(float4*)op = make_float4(v[0], v[1], v[2], v[3]);
    *(float4*)(op + 4) = make_float4(v[4], v[5], v[6], v[7]);
#pragma unroll
    for (int j = 0; j < 8; j++) { s[j] += v[j]; q[j] += v[j] * v[j]; }
  }
  // reduce stats: butterfly over ty groups within wave, then LDS across waves
#pragma unroll
  for (int j = 0; j < 8; j++) {
    s[j] += __shfl_xor(s[j], 16);
    s[j] += __shfl_xor(s[j], 32);
    q[j] += __shfl_xor(q[j], 16);
    q[j] += __shfl_xor(q[j], 32);
  }
  __syncthreads();
  float* red = &xt[0][0];  // reuse LDS (needs 1024 floats)
  if ((t & 63) < 16) {
    int w = t >> 6;
#pragma unroll
    for (int j = 0; j < 8; j++) {
      red[w * 128 + tx * 8 + j] = s[j];
      red[512 + w * 128 + tx * 8 + j] = q[j];
    }
  }
  __syncthreads();
  if (t < 128) {
    float ss = red[t] + red[128 + t] + red[256 + t] + red[384 + t];
    float qq = red[512 + t] + red[640 + t] + red[768 + t] + red[896 + t];
    atomicAdd(&esum[t], ss);
    atomicAdd(&esq[t], qq);
  }
}

// ---------------- BN stats finalize (1 block, 128 threads) ----------------
__global__ void k_finalize(const float* __restrict__ sum, const float* __restrict__ sq,
                           const float* __restrict__ gamma, const float* __restrict__ beta,
                           float* __restrict__ scale, float* __restrict__ shift, float cnt) {
  int t = threadIdx.x;
  float mean = sum[t] / cnt;
  float var = sq[t] / cnt - mean * mean;
  float sc = gamma[t] * rsqrtf(var + 1e-5f);
  scale[t] = sc;
  shift[t] = beta[t] - mean * sc;
}

// ---- edge finalize: BN+relu+residual -> edge_out (in place); sigmoid*Vx[col] -> atomic agg[row] ----
__global__ __launch_bounds__(256) void k_edge_final(const float* __restrict__ ea,
                                                    const int* __restrict__ rowi,
                                                    const int* __restrict__ coli,
                                                    const float* __restrict__ UVBC,
                                                    const float* __restrict__ escale,
                                                    const float* __restrict__ eshift,
                                                    float* __restrict__ eout,
                                                    float* __restrict__ agg) {
  const int lane = threadIdx.x & 31;
  const int rs = threadIdx.x >> 5;
  const int f = lane * 4;
  float4 sc = *(const float4*)(escale + f);
  float4 sh = *(const float4*)(eshift + f);
  for (long e = (long)blockIdx.x * 8 + rs; e < NE; e += (long)gridDim.x * 8) {
    float4 ein = *(const float4*)(eout + e * DD + f);
    float4 eav = *(const float4*)(ea + e * DD + f);
    float4 eo;
    eo.x = eav.x + fmaxf(fmaf(ein.x, sc.x, sh.x), 0.f);
    eo.y = eav.y + fmaxf(fmaf(ein.y, sc.y, sh.y), 0.f);
    eo.z = eav.z + fmaxf(fmaf(ein.z, sc.z, sh.z), 0.f);
    eo.w = eav.w + fmaxf(fmaf(ein.w, sc.w, sh.w), 0.f);
    *(float4*)(eout + e * DD + f) = eo;
    int ri = rowi[e], ci = coli[e];
    float4 vv = *(const float4*)(UVBC + (long)ci * 512 + 128 + f);
    float4 m;
    m.x = vv.x / (1.f + __expf(-eo.x));
    m.y = vv.y / (1.f + __expf(-eo.y));
    m.z = vv.z / (1.f + __expf(-eo.z));
    m.w = vv.w / (1.f + __expf(-eo.w));
    float* ag = agg + (long)ri * DD + f;
    atomicAdd(ag + 0, m.x);
    atomicAdd(ag + 1, m.y);
    atomicAdd(ag + 2, m.z);
    atomicAdd(ag + 3, m.w);
  }
}

// ---- node_in = Ux + agg (in place into agg) + node BN stats ----
__global__ __launch_bounds__(256) void k_node_stats(const float* __restrict__ UVBC,
                                                    float* __restrict__ agg,
                                                    float* __restrict__ nsum,
                                                    float* __restrict__ nsq) {
  __shared__ float red[1024];
  const int t = threadIdx.x;
  const int lane = t & 31, rs = t >> 5, f = lane * 4;
  float s[4] = {0.f, 0.f, 0.f, 0.f}, q[4] = {0.f, 0.f, 0.f, 0.f};
  for (long n = (long)blockIdx.x * 8 + rs; n < NN; n += (long)gridDim.x * 8) {
    float4 u = *(const float4*)(UVBC + n * 512 + f);
    float4 a = *(const float4*)(agg + n * DD + f);
    float4 v = make_float4(u.x + a.x, u.y + a.y, u.z + a.z, u.w + a.w);
    *(float4*)(agg + n * DD + f) = v;
    s[0] += v.x; s[1] += v.y; s[2] += v.z; s[3] += v.w;
    q[0] += v.x * v.x; q[1] += v.y * v.y; q[2] += v.z * v.z; q[3] += v.w * v.w;
  }
#pragma unroll
  for (int j = 0; j < 4; j++) {
    s[j] += __shfl_xor(s[j], 32);
    q[j] += __shfl_xor(q[j], 32);
  }
  if ((t & 63) < 32) {
    int w = t >> 6;
    *(float4*)&red[w * 128 + f] = make_float4(s[0], s[1], s[2], s[3]);
    *(float4*)&red[512 + w * 128 + f] = make_float4(q[0], q[1], q[2], q[3]);
  }
  __syncthreads();
  if (t < 128) {
    float ss = red[t] + red[128 + t] + red[256 + t] + red[384 + t];
    float qq = red[512 + t] + red[640 + t] + red[768 + t] + red[896 + t];
    atomicAdd(&nsum[t], ss);
    atomicAdd(&nsq[t], qq);
  }
}

// ---- x_out = x + relu(bn(node_in)) ----
__global__ __launch_bounds__(256) void k_node_final(const float* __restrict__ x,
                                                    const float* __restrict__ nodein,
                                                    const float* __restrict__ nscale,
                                                    const float* __restrict__ nshift,
                                                    float* __restrict__ xout) {
  const int lane = threadIdx.x & 31;
  const int rs = threadIdx.x >> 5;
  const int f = lane * 4;
  float4 sc = *(const float4*)(nscale + f);
  float4 sh = *(const float4*)(nshift + f);
  for (long n = (long)blockIdx.x * 8 + rs; n < NN; n += (long)gridDim.x * 8) {
    float4 xi = *(const float4*)(x + n * DD + f);
    float4 v = *(const float4*)(nodein + n * DD + f);
    float4 o;
    o.x = xi.x + fmaxf(fmaf(v.x, sc.x, sh.x), 0.f);
    o.y = xi.y + fmaxf(fmaf(v.y, sc.y, sh.y), 0.f);
    o.z = xi.z + fmaxf(fmaf(v.z, sc.z, sh.z), 0.f);
    o.w = xi.w + fmaxf(fmaf(v.w, sc.w, sh.w), 0.f);
    *(float4*)(xout + n * DD + f) = o;
  }
}

extern "C" void kernel_launch(void* const* d_in, const int* in_sizes, int n_in,
                              void* d_out, int out_size, void* d_ws, size_t ws_size,
                              hipStream_t stream) {
  const float* x = (const float*)d_in[0];
  const int* ei = (const int*)d_in[1];
  const float* ea = (const float*)d_in[2];
  const float* Wu = (const float*)d_in[3];
  const float* bu = (const float*)d_in[4];
  const float* Wv = (const float*)d_in[5];
  const float* bv = (const float*)d_in[6];
  const float* WA = (const float*)d_in[7];
  const float* bA = (const float*)d_in[8];
  const float* WB = (const float*)d_in[9];
  const float* bB = (const float*)d_in[10];
  const float* WC = (const float*)d_in[11];
  const float* bC = (const float*)d_in[12];
  const float* gng = (const float*)d_in[13];
  const float* gnb = (const float*)d_in[14];
  const float* geg = (const float*)d_in[15];
  const float* geb = (const float*)d_in[16];
  const int* rowi = ei;
  const int* coli = ei + NE;

  float* ws = (float*)d_ws;
  float* out = (float*)d_out;            // x_out [N][128]
  float* eout = out + (long)NN * DD;     // edge region: edge_in, then edge_out in place
  float* UVBC = ws + OFF_UVBC;
  float* agg = ws + OFF_AGG;
  float* Wp = ws + OFF_WPACK;
  float* bp = ws + OFF_BPACK;
  float* st = ws + OFF_STATS;
  float* esum = st, * esq = st + 128, * nsum = st + 256, * nsq = st + 384;
  float* escale = st + 512, * eshift = st + 640, * nscale = st + 768, * nshift = st + 896;

  k_prep<<<6512, 256, 0, stream>>>(Wu, Wv, WB, WC, bu, bv, bB, bC, ws);
  k_node_gemm<<<dim3(391, 4), 256, 0, stream>>>(x, Wp, bp, UVBC);
  k_edge_gemm<<<5000, 256, 0, stream>>>(ea, WA, bA, rowi, coli, UVBC, eout, esum, esq);
  k_finalize<<<1, 128, 0, stream>>>(esum, esq, geg, geb, escale, eshift, (float)NE);
  k_edge_final<<<2048, 256, 0, stream>>>(ea, rowi, coli, UVBC, escale, eshift, eout, agg);
  k_node_stats<<<2048, 256, 0, stream>>>(UVBC, agg, nsum, nsq);
  k_finalize<<<1, 128, 0, stream>>>(nsum, nsq, gng, gnb, nscale, nshift, (float)NN);
  k_node_final<<<2048, 256, 0, stream>>>(x, agg, nscale, nshift, out);
}

// Round 2
// 1330.303 us; speedup vs baseline: 1.5207x; 1.5207x over previous
//
#include <hip/hip_runtime.h>
#include <math.h>

#define NN 50000
#define NE 640000
#define DD 128

// ws layout (float offsets)
#define OFF_UVBC 0L
#define OFF_AGG   25600000L          // node_in lives here (write-once, no pre-zero)
#define OFF_WPACK 32000000L
#define OFF_BPACK 32065536L
#define OFF_STATS 32066048L          // esum,esq,nsum,nsq,escale,eshift,nscale,nshift (8*128)

// int scratch inside d_out's x_out region (free until k_node_final):
#define IO_PERM 0
#define IO_OFFS 640000
#define IO_CUR  692064
#define IO_CNT  744128

// ---------------- prep: pack weights/biases, zero stats + cnt ----------------
__global__ void k_prep(const float* __restrict__ Wu, const float* __restrict__ Wv,
                       const float* __restrict__ WB, const float* __restrict__ WC,
                       const float* __restrict__ bu, const float* __restrict__ bv,
                       const float* __restrict__ bB, const float* __restrict__ bC,
                       float* __restrict__ ws, int* __restrict__ cnt) {
  long i = (long)blockIdx.x * 256 + threadIdx.x;
  if (i < 65536) {
    int w = (int)(i >> 14), idx = (int)(i & 16383);
    const float* src = (w == 0) ? Wu : (w == 1) ? Wv : (w == 2) ? WB : WC;
    ws[OFF_WPACK + (long)w * 16384 + idx] = src[idx];
  } else if (i < 66048) {
    long j = i - 65536;
    int w = (int)(j >> 7), idx = (int)(j & 127);
    const float* src = (w == 0) ? bu : (w == 1) ? bv : (w == 2) ? bB : bC;
    ws[OFF_BPACK + j] = src[idx];
  } else if (i < 66560) {
    ws[OFF_STATS + (i - 66048)] = 0.f;
  } else if (i < 116560) {
    cnt[i - 66560] = 0;
  }
}

// ---------------- node GEMM: UVBC[N][512] = x @ [Wu|Wv|WB|WC].T + b ----------------
__global__ __launch_bounds__(256) void k_node_gemm(const float* __restrict__ x,
                                                   const float* __restrict__ Wp,
                                                   const float* __restrict__ bp,
                                                   float* __restrict__ out) {
  __shared__ float xt[32][132];
  __shared__ float wt[32][132];
  const int t = threadIdx.x;
  const int tx = t & 15, ty = t >> 4;
  const int rb = blockIdx.x * 128;
  const int fb = blockIdx.y * 128;
  float acc[8][8];
#pragma unroll
  for (int i = 0; i < 8; i++)
#pragma unroll
    for (int j = 0; j < 8; j++) acc[i][j] = 0.f;

  for (int kc = 0; kc < DD; kc += 32) {
#pragma unroll
    for (int s = 0; s < 4; s++) {
      int slot = t + s * 256;
      int r = slot >> 3;
      int kq = (slot & 7) << 2;
      int gr = rb + r;
      float4 v = make_float4(0.f, 0.f, 0.f, 0.f);
      if (gr < NN) v = *(const float4*)(x + (long)gr * DD + kc + kq);
      xt[kq][r] = v.x; xt[kq + 1][r] = v.y; xt[kq + 2][r] = v.z; xt[kq + 3][r] = v.w;
      float4 w = *(const float4*)(Wp + (long)(fb + r) * DD + kc + kq);
      wt[kq][r] = w.x; wt[kq + 1][r] = w.y; wt[kq + 2][r] = w.z; wt[kq + 3][r] = w.w;
    }
    __syncthreads();
#pragma unroll
    for (int k = 0; k < 32; k++) {
      float4 a0 = *(const float4*)&xt[k][ty * 8];
      float4 a1 = *(const float4*)&xt[k][ty * 8 + 4];
      float4 b0 = *(const float4*)&wt[k][tx * 8];
      float4 b1 = *(const float4*)&wt[k][tx * 8 + 4];
      float a[8] = {a0.x, a0.y, a0.z, a0.w, a1.x, a1.y, a1.z, a1.w};
      float b[8] = {b0.x, b0.y, b0.z, b0.w, b1.x, b1.y, b1.z, b1.w};
#pragma unroll
      for (int i = 0; i < 8; i++)
#pragma unroll
        for (int j = 0; j < 8; j++) acc[i][j] = fmaf(a[i], b[j], acc[i][j]);
    }
    __syncthreads();
  }
  float bb[8];
  *(float4*)&bb[0] = *(const float4*)(bp + fb + tx * 8);
  *(float4*)&bb[4] = *(const float4*)(bp + fb + tx * 8 + 4);
#pragma unroll
  for (int i = 0; i < 8; i++) {
    int gr = rb + ty * 8 + i;
    if (gr < NN) {
      float* op = out + (long)gr * 512 + fb + tx * 8;
      *(float4*)op = make_float4(acc[i][0] + bb[0], acc[i][1] + bb[1], acc[i][2] + bb[2], acc[i][3] + bb[3]);
      *(float4*)(op + 4) = make_float4(acc[i][4] + bb[4], acc[i][5] + bb[5], acc[i][6] + bb[6], acc[i][7] + bb[7]);
    }
  }
}

// ---------------- counting sort of edges by row ----------------
__global__ void k_hist(const int* __restrict__ rowi, int* __restrict__ cnt) {
  int e = blockIdx.x * 256 + threadIdx.x;
  if (e < NE) atomicAdd(&cnt[rowi[e]], 1);
}

__global__ __launch_bounds__(1024) void k_scan(const int* __restrict__ cnt,
                                               int* __restrict__ offs,
                                               int* __restrict__ cur) {
  __shared__ int wsum[17];
  const int t = threadIdx.x;
  const int lane = t & 63, w = t >> 6;
  int carry = 0;
  for (int base = 0; base < NN; base += 1024) {
    int idx = base + t;
    int v = (idx < NN) ? cnt[idx] : 0;
    int x = v;
#pragma unroll
    for (int off = 1; off < 64; off <<= 1) {
      int y = __shfl_up(x, off, 64);
      if (lane >= off) x += y;
    }
    if (lane == 63) wsum[w] = x;
    __syncthreads();
    if (t == 0) {
      int run = 0;
#pragma unroll
      for (int i = 0; i < 16; i++) { int tv = wsum[i]; wsum[i] = run; run += tv; }
      wsum[16] = run;
    }
    __syncthreads();
    int excl = x - v + wsum[w] + carry;
    if (idx < NN) { offs[idx] = excl; cur[idx] = excl; }
    carry += wsum[16];
    __syncthreads();
  }
  if (t == 0) offs[NN] = carry;
}

__global__ void k_scatter(const int* __restrict__ rowi, int* __restrict__ cur,
                          int* __restrict__ perm) {
  int e = blockIdx.x * 256 + threadIdx.x;
  if (e < NE) {
    int p = atomicAdd(&cur[rowi[e]], 1);
    perm[p] = e;
  }
}

// ---- edge GEMM: edge_in = ea@WA.T + bA + Bx[row] + Cx[col]; fused BN stats ----
__global__ __launch_bounds__(256) void k_edge_gemm(const float* __restrict__ ea,
                                                   const float* __restrict__ WA,
                                                   const float* __restrict__ bA,
                                                   const int* __restrict__ rowi,
                                                   const int* __restrict__ coli,
                                                   const float* __restrict__ UVBC,
                                                   float* __restrict__ edge_in,
                                                   float* __restrict__ esum,
                                                   float* __restrict__ esq) {
  __shared__ float xt[32][132];
  __shared__ float wt[32][132];
  const int t = threadIdx.x;
  const int tx = t & 15, ty = t >> 4;
  const int rb = blockIdx.x * 128;
  float acc[8][8];
#pragma unroll
  for (int i = 0; i < 8; i++)
#pragma unroll
    for (int j = 0; j < 8; j++) acc[i][j] = 0.f;

  for (int kc = 0; kc < DD; kc += 32) {
#pragma unroll
    for (int s = 0; s < 4; s++) {
      int slot = t + s * 256;
      int r = slot >> 3;
      int kq = (slot & 7) << 2;
      float4 v = *(const float4*)(ea + (long)(rb + r) * DD + kc + kq);
      xt[kq][r] = v.x; xt[kq + 1][r] = v.y; xt[kq + 2][r] = v.z; xt[kq + 3][r] = v.w;
      float4 w = *(const float4*)(WA + (long)r * DD + kc + kq);
      wt[kq][r] = w.x; wt[kq + 1][r] = w.y; wt[kq + 2][r] = w.z; wt[kq + 3][r] = w.w;
    }
    __syncthreads();
#pragma unroll
    for (int k = 0; k < 32; k++) {
      float4 a0 = *(const float4*)&xt[k][ty * 8];
      float4 a1 = *(const float4*)&xt[k][ty * 8 + 4];
      float4 b0 = *(const float4*)&wt[k][tx * 8];
      float4 b1 = *(const float4*)&wt[k][tx * 8 + 4];
      float a[8] = {a0.x, a0.y, a0.z, a0.w, a1.x, a1.y, a1.z, a1.w};
      float b[8] = {b0.x, b0.y, b0.z, b0.w, b1.x, b1.y, b1.z, b1.w};
#pragma unroll
      for (int i = 0; i < 8; i++)
#pragma unroll
        for (int j = 0; j < 8; j++) acc[i][j] = fmaf(a[i], b[j], acc[i][j]);
    }
    __syncthreads();
  }
  float bb[8];
  *(float4*)&bb[0] = *(const float4*)(bA + tx * 8);
  *(float4*)&bb[4] = *(const float4*)(bA + tx * 8 + 4);
  float s[8], q[8];
#pragma unroll
  for (int j = 0; j < 8; j++) { s[j] = 0.f; q[j] = 0.f; }
#pragma unroll
  for (int i = 0; i < 8; i++) {
    int e = rb + ty * 8 + i;
    int ri = rowi[e], ci = coli[e];
    const float* gB = UVBC + (long)ri * 512 + 256 + tx * 8;
    const float* gC = UVBC + (long)ci * 512 + 384 + tx * 8;
    float4 g0 = *(const float4*)gB, g1 = *(const float4*)(gB + 4);
    float4 h0 = *(const float4*)gC, h1 = *(const float4*)(gC + 4);
    float v[8];
    v[0] = acc[i][0] + bb[0] + g0.x + h0.x;
    v[1] = acc[i][1] + bb[1] + g0.y + h0.y;
    v[2] = acc[i][2] + bb[2] + g0.z + h0.z;
    v[3] = acc[i][3] + bb[3] + g0.w + h0.w;
    v[4] = acc[i][4] + bb[4] + g1.x + h1.x;
    v[5] = acc[i][5] + bb[5] + g1.y + h1.y;
    v[6] = acc[i][6] + bb[6] + g1.z + h1.z;
    v[7] = acc[i][7] + bb[7] + g1.w + h1.w;
    float* op = edge_in + (long)e * DD + tx * 8;
    *(float4*)op = make_float4(v[0], v[1], v[2], v[3]);
    *(float4*)(op + 4) = make_float4(v[4], v[5], v[6], v[7]);
#pragma unroll
    for (int j = 0; j < 8; j++) { s[j] += v[j]; q[j] += v[j] * v[j]; }
  }
#pragma unroll
  for (int j = 0; j < 8; j++) {
    s[j] += __shfl_xor(s[j], 16);
    s[j] += __shfl_xor(s[j], 32);
    q[j] += __shfl_xor(q[j], 16);
    q[j] += __shfl_xor(q[j], 32);
  }
  __syncthreads();
  float* red = &xt[0][0];
  if ((t & 63) < 16) {
    int w = t >> 6;
#pragma unroll
    for (int j = 0; j < 8; j++) {
      red[w * 128 + tx * 8 + j] = s[j];
      red[512 + w * 128 + tx * 8 + j] = q[j];
    }
  }
  __syncthreads();
  if (t < 128) {
    float ss = red[t] + red[128 + t] + red[256 + t] + red[384 + t];
    float qq = red[512 + t] + red[640 + t] + red[768 + t] + red[896 + t];
    atomicAdd(&esum[t], ss);
    atomicAdd(&esq[t], qq);
  }
}

// ---------------- BN stats finalize ----------------
__global__ void k_finalize(const float* __restrict__ sum, const float* __restrict__ sq,
                           const float* __restrict__ gamma, const float* __restrict__ beta,
                           float* __restrict__ scale, float* __restrict__ shift, float cnt) {
  int t = threadIdx.x;
  float mean = sum[t] / cnt;
  float var = sq[t] / cnt - mean * mean;
  float sc = gamma[t] * rsqrtf(var + 1e-5f);
  scale[t] = sc;
  shift[t] = beta[t] - mean * sc;
}

// ---- edge finalize: eout = ea + relu(bn(ein))  (pure streaming, in place) ----
__global__ __launch_bounds__(256) void k_edge_final(const float* __restrict__ ea,
                                                    const float* __restrict__ escale,
                                                    const float* __restrict__ eshift,
                                                    float* __restrict__ eout) {
  const long TOT = (long)NE * DD / 4;  // float4 elements
  const int f = (threadIdx.x & 31) * 4;
  float4 sc = *(const float4*)(escale + f);
  float4 sh = *(const float4*)(eshift + f);
  const long stride = (long)gridDim.x * 256;
  for (long i = (long)blockIdx.x * 256 + threadIdx.x; i < TOT; i += stride) {
    float4 ein = ((const float4*)eout)[i];
    float4 eav = ((const float4*)ea)[i];
    float4 eo;
    eo.x = eav.x + fmaxf(fmaf(ein.x, sc.x, sh.x), 0.f);
    eo.y = eav.y + fmaxf(fmaf(ein.y, sc.y, sh.y), 0.f);
    eo.z = eav.z + fmaxf(fmaf(ein.z, sc.z, sh.z), 0.f);
    eo.w = eav.w + fmaxf(fmaf(ein.w, sc.w, sh.w), 0.f);
    ((float4*)eout)[i] = eo;
  }
}

// ---- aggregate: per half-wave per node, msg-sum over sorted edge list; fuse node_in + BN stats ----
__global__ __launch_bounds__(256) void k_aggregate(const int* __restrict__ perm,
                                                   const int* __restrict__ offs,
                                                   const int* __restrict__ coli,
                                                   const float* __restrict__ eout,
                                                   const float* __restrict__ UVBC,
                                                   float* __restrict__ nodein,
                                                   float* __restrict__ nsum,
                                                   float* __restrict__ nsq) {
  __shared__ float red[2048];
  const int t = threadIdx.x;
  const int hw = t >> 5, lane = t & 31;
  const int f = lane * 4;
  float4 s = make_float4(0.f, 0.f, 0.f, 0.f);
  float4 q = make_float4(0.f, 0.f, 0.f, 0.f);
  for (int n = blockIdx.x * 8 + hw; n < NN; n += gridDim.x * 8) {
    int beg = offs[n], end = offs[n + 1];
    float4 acc = make_float4(0.f, 0.f, 0.f, 0.f);
    for (int i = beg; i < end; i++) {
      int e = perm[i];
      int ci = coli[e];
      float4 eo = *(const float4*)(eout + (long)e * DD + f);
      float4 vv = *(const float4*)(UVBC + (long)ci * 512 + 128 + f);
      float4 sg;
      sg.x = 1.f / (1.f + __expf(-eo.x));
      sg.y = 1.f / (1.f + __expf(-eo.y));
      sg.z = 1.f / (1.f + __expf(-eo.z));
      sg.w = 1.f / (1.f + __expf(-eo.w));
      acc.x = fmaf(sg.x, vv.x, acc.x);
      acc.y = fmaf(sg.y, vv.y, acc.y);
      acc.z = fmaf(sg.z, vv.z, acc.z);
      acc.w = fmaf(sg.w, vv.w, acc.w);
    }
    float4 u = *(const float4*)(UVBC + (long)n * 512 + f);
    float4 v = make_float4(acc.x + u.x, acc.y + u.y, acc.z + u.z, acc.w + u.w);
    *(float4*)(nodein + (long)n * DD + f) = v;
    s.x += v.x; s.y += v.y; s.z += v.z; s.w += v.w;
    q.x += v.x * v.x; q.y += v.y * v.y; q.z += v.z * v.z; q.w += v.w * v.w;
  }
  *(float4*)&red[hw * 128 + f] = s;
  *(float4*)&red[1024 + hw * 128 + f] = q;
  __syncthreads();
  if (t < 128) {
    float ss = 0.f, qq = 0.f;
#pragma unroll
    for (int w = 0; w < 8; w++) {
      ss += red[w * 128 + t];
      qq += red[1024 + w * 128 + t];
    }
    atomicAdd(&nsum[t], ss);
    atomicAdd(&nsq[t], qq);
  }
}

// ---- x_out = x + relu(bn(node_in)) ----
__global__ __launch_bounds__(256) void k_node_final(const float* __restrict__ x,
                                                    const float* __restrict__ nodein,
                                                    const float* __restrict__ nscale,
                                                    const float* __restrict__ nshift,
                                                    float* __restrict__ xout) {
  const long TOT = (long)NN * DD / 4;
  const int f = (threadIdx.x & 31) * 4;
  float4 sc = *(const float4*)(nscale + f);
  float4 sh = *(const float4*)(nshift + f);
  const long stride = (long)gridDim.x * 256;
  for (long i = (long)blockIdx.x * 256 + threadIdx.x; i < TOT; i += stride) {
    float4 xi = ((const float4*)x)[i];
    float4 v = ((const float4*)nodein)[i];
    float4 o;
    o.x = xi.x + fmaxf(fmaf(v.x, sc.x, sh.x), 0.f);
    o.y = xi.y + fmaxf(fmaf(v.y, sc.y, sh.y), 0.f);
    o.z = xi.z + fmaxf(fmaf(v.z, sc.z, sh.z), 0.f);
    o.w = xi.w + fmaxf(fmaf(v.w, sc.w, sh.w), 0.f);
    ((float4*)xout)[i] = o;
  }
}

extern "C" void kernel_launch(void* const* d_in, const int* in_sizes, int n_in,
                              void* d_out, int out_size, void* d_ws, size_t ws_size,
                              hipStream_t stream) {
  const float* x = (const float*)d_in[0];
  const int* ei = (const int*)d_in[1];
  const float* ea = (const float*)d_in[2];
  const float* Wu = (const float*)d_in[3];
  const float* bu = (const float*)d_in[4];
  const float* Wv = (const float*)d_in[5];
  const float* bv = (const float*)d_in[6];
  const float* WA = (const float*)d_in[7];
  const float* bA = (const float*)d_in[8];
  const float* WB = (const float*)d_in[9];
  const float* bB = (const float*)d_in[10];
  const float* WC = (const float*)d_in[11];
  const float* bC = (const float*)d_in[12];
  const float* gng = (const float*)d_in[13];
  const float* gnb = (const float*)d_in[14];
  const float* geg = (const float*)d_in[15];
  const float* geb = (const float*)d_in[16];
  const int* rowi = ei;
  const int* coli = ei + NE;

  float* ws = (float*)d_ws;
  float* out = (float*)d_out;             // x_out [N][128] (scratch for sort until the end)
  float* eout = out + (long)NN * DD;      // edge region: edge_in then edge_out in place
  float* UVBC = ws + OFF_UVBC;
  float* nodein = ws + OFF_AGG;
  float* Wp = ws + OFF_WPACK;
  float* bp = ws + OFF_BPACK;
  float* st = ws + OFF_STATS;
  float* esum = st, * esq = st + 128, * nsum = st + 256, * nsq = st + 384;
  float* escale = st + 512, * eshift = st + 640, * nscale = st + 768, * nshift = st + 896;

  int* iout = (int*)d_out;
  int* perm = iout + IO_PERM;
  int* offs = iout + IO_OFFS;
  int* cur = iout + IO_CUR;
  int* cnt = iout + IO_CNT;

  k_prep<<<456, 256, 0, stream>>>(Wu, Wv, WB, WC, bu, bv, bB, bC, ws, cnt);
  k_node_gemm<<<dim3(391, 4), 256, 0, stream>>>(x, Wp, bp, UVBC);
  k_hist<<<2500, 256, 0, stream>>>(rowi, cnt);
  k_scan<<<1, 1024, 0, stream>>>(cnt, offs, cur);
  k_scatter<<<2500, 256, 0, stream>>>(rowi, cur, perm);
  k_edge_gemm<<<5000, 256, 0, stream>>>(ea, WA, bA, rowi, coli, UVBC, eout, esum, esq);
  k_finalize<<<1, 128, 0, stream>>>(esum, esq, geg, geb, escale, eshift, (float)NE);
  k_edge_final<<<4096, 256, 0, stream>>>(ea, escale, eshift, eout);
  k_aggregate<<<1024, 256, 0, stream>>>(perm, offs, coli, eout, UVBC, nodein, nsum, nsq);
  k_finalize<<<1, 128, 0, stream>>>(nsum, nsq, gng, gnb, nscale, nshift, (float)NN);
  k_node_final<<<2048, 256, 0, stream>>>(x, nodein, nscale, nshift, out);
}

// Round 3
// 1213.324 us; speedup vs baseline: 1.6673x; 1.0964x over previous
//
#include <hip/hip_runtime.h>
#include <math.h>

#define NN 50000
#define NE 640000
#define DD 128

// ws layout (float offsets)
#define OFF_UVBC   0L            // [N][512] f32
#define OFF_NODEIN 25600000L     // [N][128] f32
#define OFF_WNH    32000000L     // [512][128] bf16 hi (32768 fl)
#define OFF_WNL    32032768L     // [512][128] bf16 lo
#define OFF_WAH    32065536L     // [128][128] bf16 hi (8192 fl)
#define OFF_WAL    32073728L     // [128][128] bf16 lo
#define OFF_BN     32081920L     // 512 f32 packed node biases
#define OFF_STATS  32082432L     // 1024 f32: esum,esq,nsum,nsq,escale,eshift,nscale,nshift

// int scratch inside d_out's x_out region (free until k_node_final)
#define IO_PERM 0
#define IO_OFFS 640000
#define IO_CUR  692000
#define IO_CNT  744000
#define IO_AUX  796000
#define NBLK_SCAN 196

typedef __attribute__((ext_vector_type(4))) float f32x4;
typedef __attribute__((ext_vector_type(8))) short short8v;

__device__ inline short f2bf(float x) {
  unsigned u = __float_as_uint(x);
  return (short)((u + 0x7fffu + ((u >> 16) & 1u)) >> 16);
}
__device__ inline float bf2f(short b) {
  return __uint_as_float(((unsigned)(unsigned short)b) << 16);
}

// ---------------- prep: split weights to bf16 hi/lo, pack biases, zero stats+cnt ----------------
__global__ void k_prep(const float* __restrict__ Wu, const float* __restrict__ Wv,
                       const float* __restrict__ WB, const float* __restrict__ WC,
                       const float* __restrict__ WAw,
                       const float* __restrict__ bu, const float* __restrict__ bv,
                       const float* __restrict__ bB, const float* __restrict__ bC,
                       float* __restrict__ ws, int* __restrict__ cnt) {
  long i = (long)blockIdx.x * 256 + threadIdx.x;
  short* WnH = (short*)(ws + OFF_WNH);
  short* WnL = (short*)(ws + OFF_WNL);
  short* WAH = (short*)(ws + OFF_WAH);
  short* WAL = (short*)(ws + OFF_WAL);
  if (i < 65536) {
    int fidx = (int)(i >> 7), k = (int)(i & 127);
    int wsel = fidx >> 7, frow = fidx & 127;
    const float* src = (wsel == 0) ? Wu : (wsel == 1) ? Wv : (wsel == 2) ? WB : WC;
    float v = src[frow * 128 + k];
    short hb = f2bf(v);
    WnH[i] = hb; WnL[i] = f2bf(v - bf2f(hb));
  } else if (i < 81920) {
    long j = i - 65536;
    float v = WAw[j];
    short hb = f2bf(v);
    WAH[j] = hb; WAL[j] = f2bf(v - bf2f(hb));
  } else if (i < 82432) {
    long j = i - 81920;  // 0..511
    int wsel = (int)(j >> 7), k = (int)(j & 127);
    const float* src = (wsel == 0) ? bu : (wsel == 1) ? bv : (wsel == 2) ? bB : bC;
    ws[OFF_BN + j] = src[k];
  } else if (i < 83456) {
    ws[OFF_STATS + (i - 82432)] = 0.f;
  } else if (i < 133456) {
    cnt[i - 83456] = 0;
  }
}

// ---------------- node GEMM (MFMA): UVBC[N][512] = x @ [Wu|Wv|WB|WC].T + b ----------------
__global__ __launch_bounds__(256) void k_node_gemm(const float* __restrict__ x,
                                                   const short* __restrict__ WnH,
                                                   const short* __restrict__ WnL,
                                                   const float* __restrict__ bn,
                                                   float* __restrict__ UVBC) {
  const int t = threadIdx.x, w = t >> 6, lane = t & 63, cl = lane & 15, h = lane >> 4;
  const long r0 = (long)blockIdx.x * 128 + w * 32;
  short8v ahi[2][4], alo[2][4];
#pragma unroll
  for (int rb = 0; rb < 2; rb++) {
    long row = r0 + rb * 16 + cl;
    bool ok = row < NN;
    const float* ap = x + row * 128 + h * 8;
#pragma unroll
    for (int ks = 0; ks < 4; ks++) {
      f32x4 ra = ok ? *(const f32x4*)(ap + ks * 32) : (f32x4)0.f;
      f32x4 rc = ok ? *(const f32x4*)(ap + ks * 32 + 4) : (f32x4)0.f;
#pragma unroll
      for (int j = 0; j < 4; j++) {
        short hb = f2bf(ra[j]);
        ahi[rb][ks][j] = hb; alo[rb][ks][j] = f2bf(ra[j] - bf2f(hb));
        short hb2 = f2bf(rc[j]);
        ahi[rb][ks][4 + j] = hb2; alo[rb][ks][4 + j] = f2bf(rc[j] - bf2f(hb2));
      }
    }
  }
#pragma unroll 1
  for (int p = 0; p < 4; p++) {
    f32x4 acc[2][8];
#pragma unroll
    for (int rb = 0; rb < 2; rb++)
#pragma unroll
      for (int cb = 0; cb < 8; cb++) acc[rb][cb] = (f32x4)0.f;
#pragma unroll
    for (int ks = 0; ks < 4; ks++) {
#pragma unroll
      for (int cb = 0; cb < 8; cb++) {
        long boff = ((long)(p * 128 + cb * 16 + cl)) * 128 + ks * 32 + h * 8;
        short8v bh = *(const short8v*)(WnH + boff);
        short8v bl = *(const short8v*)(WnL + boff);
#pragma unroll
        for (int rb = 0; rb < 2; rb++) {
          acc[rb][cb] = __builtin_amdgcn_mfma_f32_16x16x32_bf16(ahi[rb][ks], bh, acc[rb][cb], 0, 0, 0);
          acc[rb][cb] = __builtin_amdgcn_mfma_f32_16x16x32_bf16(ahi[rb][ks], bl, acc[rb][cb], 0, 0, 0);
          acc[rb][cb] = __builtin_amdgcn_mfma_f32_16x16x32_bf16(alo[rb][ks], bh, acc[rb][cb], 0, 0, 0);
        }
      }
    }
#pragma unroll
    for (int cb = 0; cb < 8; cb++) {
      int c = p * 128 + cb * 16 + cl;
      float bias = bn[c];
#pragma unroll
      for (int rb = 0; rb < 2; rb++)
#pragma unroll
        for (int reg = 0; reg < 4; reg++) {
          long row = r0 + rb * 16 + h * 4 + reg;
          if (row < NN) UVBC[row * 512 + c] = acc[rb][cb][reg] + bias;
        }
    }
  }
}

// ---- edge GEMM (MFMA): edge_in = ea@WA.T + bA + Bx[row] + Cx[col]; fused BN stats ----
__global__ __launch_bounds__(256) void k_edge_gemm(const float* __restrict__ ea,
                                                   const short* __restrict__ WAH,
                                                   const short* __restrict__ WAL,
                                                   const float* __restrict__ bA,
                                                   const int* __restrict__ rowi,
                                                   const int* __restrict__ coli,
                                                   const float* __restrict__ UVBC,
                                                   float* __restrict__ edge_in,
                                                   float* __restrict__ esum,
                                                   float* __restrict__ esq) {
  __shared__ float red[2048];
  const int t = threadIdx.x, w = t >> 6, lane = t & 63, cl = lane & 15, h = lane >> 4;
  const long r0 = (long)blockIdx.x * 128 + w * 32;  // NE divisible by 128
  short8v ahi[2][4], alo[2][4];
#pragma unroll
  for (int rb = 0; rb < 2; rb++) {
    const float* ap = ea + (r0 + rb * 16 + cl) * 128 + h * 8;
#pragma unroll
    for (int ks = 0; ks < 4; ks++) {
      f32x4 ra = *(const f32x4*)(ap + ks * 32);
      f32x4 rc = *(const f32x4*)(ap + ks * 32 + 4);
#pragma unroll
      for (int j = 0; j < 4; j++) {
        short hb = f2bf(ra[j]);
        ahi[rb][ks][j] = hb; alo[rb][ks][j] = f2bf(ra[j] - bf2f(hb));
        short hb2 = f2bf(rc[j]);
        ahi[rb][ks][4 + j] = hb2; alo[rb][ks][4 + j] = f2bf(rc[j] - bf2f(hb2));
      }
    }
  }
  f32x4 acc[2][8];
#pragma unroll
  for (int rb = 0; rb < 2; rb++)
#pragma unroll
    for (int cb = 0; cb < 8; cb++) acc[rb][cb] = (f32x4)0.f;
#pragma unroll
  for (int ks = 0; ks < 4; ks++) {
#pragma unroll
    for (int cb = 0; cb < 8; cb++) {
      long boff = ((long)(cb * 16 + cl)) * 128 + ks * 32 + h * 8;
      short8v bh = *(const short8v*)(WAH + boff);
      short8v bl = *(const short8v*)(WAL + boff);
#pragma unroll
      for (int rb = 0; rb < 2; rb++) {
        acc[rb][cb] = __builtin_amdgcn_mfma_f32_16x16x32_bf16(ahi[rb][ks], bh, acc[rb][cb], 0, 0, 0);
        acc[rb][cb] = __builtin_amdgcn_mfma_f32_16x16x32_bf16(ahi[rb][ks], bl, acc[rb][cb], 0, 0, 0);
        acc[rb][cb] = __builtin_amdgcn_mfma_f32_16x16x32_bf16(alo[rb][ks], bh, acc[rb][cb], 0, 0, 0);
      }
    }
  }
  // epilogue in fragment domain: bias + gathers + store + per-column stats
  float ba[8];
#pragma unroll
  for (int cb = 0; cb < 8; cb++) ba[cb] = bA[cb * 16 + cl];
  float s[8], q[8];
#pragma unroll
  for (int cb = 0; cb < 8; cb++) { s[cb] = 0.f; q[cb] = 0.f; }
#pragma unroll
  for (int rb = 0; rb < 2; rb++)
#pragma unroll
    for (int reg = 0; reg < 4; reg++) {
      long e = r0 + rb * 16 + h * 4 + reg;
      int ri = rowi[e], ci = coli[e];
      const float* gB = UVBC + (long)ri * 512 + 256;
      const float* gC = UVBC + (long)ci * 512 + 384;
      float* op = edge_in + e * 128;
#pragma unroll
      for (int cb = 0; cb < 8; cb++) {
        int c = cb * 16 + cl;
        float v = acc[rb][cb][reg] + ba[cb] + gB[c] + gC[c];
        op[c] = v;
        s[cb] += v; q[cb] += v * v;
      }
    }
#pragma unroll
  for (int cb = 0; cb < 8; cb++) {
    s[cb] += __shfl_xor(s[cb], 16); s[cb] += __shfl_xor(s[cb], 32);
    q[cb] += __shfl_xor(q[cb], 16); q[cb] += __shfl_xor(q[cb], 32);
  }
  if ((t & 63) < 16) {
    int wv = t >> 6, c2 = t & 15;
#pragma unroll
    for (int cb = 0; cb < 8; cb++) {
      red[wv * 128 + cb * 16 + c2] = s[cb];
      red[1024 + wv * 128 + cb * 16 + c2] = q[cb];
    }
  }
  __syncthreads();
  if (t < 128) {
    float ss = red[t] + red[128 + t] + red[256 + t] + red[384 + t];
    float qq = red[1024 + t] + red[1152 + t] + red[1280 + t] + red[1408 + t];
    atomicAdd(&esum[t], ss);
    atomicAdd(&esq[t], qq);
  }
}

// ---------------- counting sort of edges by row ----------------
__global__ void k_hist(const int* __restrict__ rowi, int* __restrict__ cnt) {
  int e = blockIdx.x * 256 + threadIdx.x;
  if (e < NE) atomicAdd(&cnt[rowi[e]], 1);
}

__global__ __launch_bounds__(256) void k_scan1(const int* __restrict__ cnt,
                                               int* __restrict__ offs,
                                               int* __restrict__ aux) {
  __shared__ int s[512];
  const int t = threadIdx.x;
  int idx = blockIdx.x * 256 + t;
  int v = (idx < NN) ? cnt[idx] : 0;
  int cur = 0, nxt = 256;
  s[t] = v;
  __syncthreads();
  for (int off = 1; off < 256; off <<= 1) {
    int val = s[cur + t];
    if (t >= off) val += s[cur + t - off];
    s[nxt + t] = val;
    __syncthreads();
    int tmp = cur; cur = nxt; nxt = tmp;
  }
  int incl = s[cur + t];
  if (idx < NN) offs[idx] = incl - v;
  if (t == 255) aux[blockIdx.x] = incl;
}

__global__ __launch_bounds__(256) void k_scan2(int* __restrict__ aux, int* __restrict__ offs) {
  __shared__ int s[512];
  const int t = threadIdx.x;
  int v = (t < NBLK_SCAN) ? aux[t] : 0;
  int cur = 0, nxt = 256;
  s[t] = v;
  __syncthreads();
  for (int off = 1; off < 256; off <<= 1) {
    int val = s[cur + t];
    if (t >= off) val += s[cur + t - off];
    s[nxt + t] = val;
    __syncthreads();
    int tmp = cur; cur = nxt; nxt = tmp;
  }
  int incl = s[cur + t];
  if (t < NBLK_SCAN) aux[t] = incl - v;
  if (t == 0) offs[NN] = NE;
}

__global__ void k_scan3(int* __restrict__ offs, const int* __restrict__ aux,
                        int* __restrict__ cur) {
  int idx = blockIdx.x * 256 + threadIdx.x;
  if (idx < NN) {
    int o = offs[idx] + aux[blockIdx.x];
    offs[idx] = o;
    cur[idx] = o;
  }
}

__global__ void k_scatter(const int* __restrict__ rowi, int* __restrict__ cur,
                          int* __restrict__ perm) {
  int e = blockIdx.x * 256 + threadIdx.x;
  if (e < NE) {
    int p = atomicAdd(&cur[rowi[e]], 1);
    perm[p] = e;
  }
}

// ---------------- BN stats finalize ----------------
__global__ void k_finalize(const float* __restrict__ sum, const float* __restrict__ sq,
                           const float* __restrict__ gamma, const float* __restrict__ beta,
                           float* __restrict__ scale, float* __restrict__ shift, float cnt) {
  int t = threadIdx.x;
  float mean = sum[t] / cnt;
  float var = sq[t] / cnt - mean * mean;
  float sc = gamma[t] * rsqrtf(var + 1e-5f);
  scale[t] = sc;
  shift[t] = beta[t] - mean * sc;
}

// ---- merged: eout = ea + relu(bn(ein)) (write once); msg agg; node_in + node BN stats ----
__global__ __launch_bounds__(256) void k_aggfinal(const int* __restrict__ perm,
                                                  const int* __restrict__ offs,
                                                  const int* __restrict__ coli,
                                                  const float* __restrict__ ea,
                                                  const float* __restrict__ escale,
                                                  const float* __restrict__ eshift,
                                                  const float* __restrict__ UVBC,
                                                  float* __restrict__ eio,
                                                  float* __restrict__ nodein,
                                                  float* __restrict__ nsum,
                                                  float* __restrict__ nsq) {
  __shared__ float red[2048];
  const int t = threadIdx.x, hw = t >> 5, lane = t & 31, f = lane * 4;
  float4 sc = *(const float4*)(escale + f);
  float4 sh = *(const float4*)(eshift + f);
  float4 s = make_float4(0.f, 0.f, 0.f, 0.f);
  float4 q = make_float4(0.f, 0.f, 0.f, 0.f);
  for (int n = blockIdx.x * 8 + hw; n < NN; n += gridDim.x * 8) {
    int beg = offs[n], end = offs[n + 1];
    float4 acc = make_float4(0.f, 0.f, 0.f, 0.f);
    for (int i = beg; i < end; i++) {
      int e = perm[i];
      int ci = coli[e];
      float4 ein = *(const float4*)(eio + (long)e * 128 + f);
      float4 eav = *(const float4*)(ea + (long)e * 128 + f);
      float4 eo;
      eo.x = eav.x + fmaxf(fmaf(ein.x, sc.x, sh.x), 0.f);
      eo.y = eav.y + fmaxf(fmaf(ein.y, sc.y, sh.y), 0.f);
      eo.z = eav.z + fmaxf(fmaf(ein.z, sc.z, sh.z), 0.f);
      eo.w = eav.w + fmaxf(fmaf(ein.w, sc.w, sh.w), 0.f);
      *(float4*)(eio + (long)e * 128 + f) = eo;
      float4 vv = *(const float4*)(UVBC + (long)ci * 512 + 128 + f);
      acc.x = fmaf(1.f / (1.f + __expf(-eo.x)), vv.x, acc.x);
      acc.y = fmaf(1.f / (1.f + __expf(-eo.y)), vv.y, acc.y);
      acc.z = fmaf(1.f / (1.f + __expf(-eo.z)), vv.z, acc.z);
      acc.w = fmaf(1.f / (1.f + __expf(-eo.w)), vv.w, acc.w);
    }
    float4 u = *(const float4*)(UVBC + (long)n * 512 + f);
    float4 v = make_float4(acc.x + u.x, acc.y + u.y, acc.z + u.z, acc.w + u.w);
    *(float4*)(nodein + (long)n * 128 + f) = v;
    s.x += v.x; s.y += v.y; s.z += v.z; s.w += v.w;
    q.x += v.x * v.x; q.y += v.y * v.y; q.z += v.z * v.z; q.w += v.w * v.w;
  }
  *(float4*)&red[hw * 128 + f] = s;
  *(float4*)&red[1024 + hw * 128 + f] = q;
  __syncthreads();
  if (t < 128) {
    float ss = 0.f, qq = 0.f;
#pragma unroll
    for (int wv = 0; wv < 8; wv++) {
      ss += red[wv * 128 + t];
      qq += red[1024 + wv * 128 + t];
    }
    atomicAdd(&nsum[t], ss);
    atomicAdd(&nsq[t], qq);
  }
}

// ---- x_out = x + relu(bn(node_in)) ----
__global__ __launch_bounds__(256) void k_node_final(const float* __restrict__ x,
                                                    const float* __restrict__ nodein,
                                                    const float* __restrict__ nscale,
                                                    const float* __restrict__ nshift,
                                                    float* __restrict__ xout) {
  const long TOT = (long)NN * DD / 4;
  const int f = (threadIdx.x & 31) * 4;
  float4 sc = *(const float4*)(nscale + f);
  float4 sh = *(const float4*)(nshift + f);
  const long stride = (long)gridDim.x * 256;
  for (long i = (long)blockIdx.x * 256 + threadIdx.x; i < TOT; i += stride) {
    float4 xi = ((const float4*)x)[i];
    float4 v = ((const float4*)nodein)[i];
    float4 o;
    o.x = xi.x + fmaxf(fmaf(v.x, sc.x, sh.x), 0.f);
    o.y = xi.y + fmaxf(fmaf(v.y, sc.y, sh.y), 0.f);
    o.z = xi.z + fmaxf(fmaf(v.z, sc.z, sh.z), 0.f);
    o.w = xi.w + fmaxf(fmaf(v.w, sc.w, sh.w), 0.f);
    ((float4*)xout)[i] = o;
  }
}

extern "C" void kernel_launch(void* const* d_in, const int* in_sizes, int n_in,
                              void* d_out, int out_size, void* d_ws, size_t ws_size,
                              hipStream_t stream) {
  const float* x = (const float*)d_in[0];
  const int* ei = (const int*)d_in[1];
  const float* ea = (const float*)d_in[2];
  const float* Wu = (const float*)d_in[3];
  const float* bu = (const float*)d_in[4];
  const float* Wv = (const float*)d_in[5];
  const float* bv = (const float*)d_in[6];
  const float* WAw = (const float*)d_in[7];
  const float* bA = (const float*)d_in[8];
  const float* WB = (const float*)d_in[9];
  const float* bB = (const float*)d_in[10];
  const float* WC = (const float*)d_in[11];
  const float* bC = (const float*)d_in[12];
  const float* gng = (const float*)d_in[13];
  const float* gnb = (const float*)d_in[14];
  const float* geg = (const float*)d_in[15];
  const float* geb = (const float*)d_in[16];
  const int* rowi = ei;
  const int* coli = ei + NE;

  float* ws = (float*)d_ws;
  float* out = (float*)d_out;
  float* eout = out + (long)NN * DD;  // edge region: edge_in, then edge_out in place
  float* UVBC = ws + OFF_UVBC;
  float* nodein = ws + OFF_NODEIN;
  const short* WnH = (const short*)(ws + OFF_WNH);
  const short* WnL = (const short*)(ws + OFF_WNL);
  const short* WAH = (const short*)(ws + OFF_WAH);
  const short* WAL = (const short*)(ws + OFF_WAL);
  float* bn = ws + OFF_BN;
  float* st = ws + OFF_STATS;
  float* esum = st, * esq = st + 128, * nsum = st + 256, * nsq = st + 384;
  float* escale = st + 512, * eshift = st + 640, * nscale = st + 768, * nshift = st + 896;

  int* iout = (int*)d_out;
  int* perm = iout + IO_PERM;
  int* offs = iout + IO_OFFS;
  int* cur = iout + IO_CUR;
  int* cnt = iout + IO_CNT;
  int* aux = iout + IO_AUX;

  k_prep<<<522, 256, 0, stream>>>(Wu, Wv, WB, WC, WAw, bu, bv, bB, bC, ws, cnt);
  k_node_gemm<<<391, 256, 0, stream>>>(x, WnH, WnL, bn, UVBC);
  k_hist<<<2500, 256, 0, stream>>>(rowi, cnt);
  k_scan1<<<NBLK_SCAN, 256, 0, stream>>>(cnt, offs, aux);
  k_scan2<<<1, 256, 0, stream>>>(aux, offs);
  k_scan3<<<NBLK_SCAN, 256, 0, stream>>>(offs, aux, cur);
  k_scatter<<<2500, 256, 0, stream>>>(rowi, cur, perm);
  k_edge_gemm<<<5000, 256, 0, stream>>>(ea, WAH, WAL, bA, rowi, coli, UVBC, eout, esum, esq);
  k_finalize<<<1, 128, 0, stream>>>(esum, esq, geg, geb, escale, eshift, (float)NE);
  k_aggfinal<<<1024, 256, 0, stream>>>(perm, offs, coli, ea, escale, eshift, UVBC, eout, nodein, nsum, nsq);
  k_finalize<<<1, 128, 0, stream>>>(nsum, nsq, gng, gnb, nscale, nshift, (float)NN);
  k_node_final<<<2048, 256, 0, stream>>>(x, nodein, nscale, nshift, out);
}